// Round 4
// baseline (56.664 us; speedup 1.0000x reference)
//
#include <hip/hip_runtime.h>

#define KERNEL_LEN 128
#define INPUT_LEN 1000000
#define PATH_NUM 10
#define L_TOTAL (INPUT_LEN + KERNEL_LEN)
#define NBLOCKS 2048
#define BLOCK_SIZE 256
#define CHUNK 4

typedef int v4i __attribute__((ext_vector_type(4)));

__global__ __launch_bounds__(BLOCK_SIZE) void dtw_spring_npath_kernel(
    const float* __restrict__ kern,
    const float* __restrict__ x,
    const int*   __restrict__ path_k,
    const int*   __restrict__ path_i,
    const int*   __restrict__ path_length,
    const int*   __restrict__ path_num,
    float*       __restrict__ out)
{
    __shared__ float k_lds[KERNEL_LEN];
    const int tid = threadIdx.x;
    if (tid < KERNEL_LEN) k_lds[tid] = kern[tid];
    __syncthreads();

    const int n = min(path_num[0], PATH_NUM);

    float acc[PATH_NUM];
    #pragma unroll
    for (int p = 0; p < PATH_NUM; ++p) acc[p] = 0.0f;

    const int start  = (blockIdx.x * BLOCK_SIZE + tid) * CHUNK;
    const int stride = NBLOCKS * BLOCK_SIZE * CHUNK;   // 2M > L: exactly 1 iter/path

    #pragma unroll
    for (int p = 0; p < PATH_NUM; ++p) {
        if (p < n) {                                   // uniform guard
            const int len  = path_length[p];
            const int len4 = len & ~(CHUNK - 1);
            const int* __restrict__ pk = path_k + (size_t)p * L_TOTAL;
            const int* __restrict__ pi = path_i + (size_t)p * L_TOTAL;

            float a = 0.0f;
            for (int t = start; t < len4; t += stride) {
                // ONE CHANGE vs R3: nontemporal on the one-touch index streams
                // so they don't evict x's 4MB working set from the 4MB/XCD L2.
                // x gathers stay temporal (want them L2-resident).
                const v4i ik = __builtin_nontemporal_load(
                                   reinterpret_cast<const v4i*>(pk + t));
                const v4i ii = __builtin_nontemporal_load(
                                   reinterpret_cast<const v4i*>(pi + t));
                const float x0 = x[(unsigned)ii[0]];
                const float x1 = x[(unsigned)ii[1]];
                const float x2 = x[(unsigned)ii[2]];
                const float x3 = x[(unsigned)ii[3]];
                const float d0 = k_lds[(unsigned)ik[0]] - x0;
                const float d1 = k_lds[(unsigned)ik[1]] - x1;
                const float d2 = k_lds[(unsigned)ik[2]] - x2;
                const float d3 = k_lds[(unsigned)ik[3]] - x3;
                a = fmaf(d0, d0, a);
                a = fmaf(d1, d1, a);
                a = fmaf(d2, d2, a);
                a = fmaf(d3, d3, a);
            }
            // tail (< 4 elements): block 0 only
            if (blockIdx.x == 0) {
                const int t = len4 + tid;
                if (t < len) {
                    const float d = k_lds[pk[t]] - x[pi[t]];
                    a = fmaf(d, d, a);
                }
            }
            acc[p] = a;
        }
    }

    // per-wave reduce all paths, then cross-wave via LDS
    __shared__ float wsum[PATH_NUM][BLOCK_SIZE / 64];
    const int wave = tid >> 6;
    const int lane = tid & 63;
    #pragma unroll
    for (int p = 0; p < PATH_NUM; ++p) {
        float a = acc[p];
        #pragma unroll
        for (int off = 32; off > 0; off >>= 1)
            a += __shfl_down(a, off, 64);
        if (lane == 0) wsum[p][wave] = a;
    }
    __syncthreads();
    if (tid < PATH_NUM && tid < n) {
        const float s = wsum[tid][0] + wsum[tid][1] + wsum[tid][2] + wsum[tid][3];
        if (s != 0.0f) atomicAdd(&out[tid], s);   // skip: blocks past this path's end
    }
}

extern "C" void kernel_launch(void* const* d_in, const int* in_sizes, int n_in,
                              void* d_out, int out_size, void* d_ws, size_t ws_size,
                              hipStream_t stream) {
    const float* kern        = (const float*)d_in[0];
    const float* x           = (const float*)d_in[1];
    const int*   path_k      = (const int*)d_in[2];
    const int*   path_i      = (const int*)d_in[3];
    const int*   path_length = (const int*)d_in[4];
    const int*   path_num    = (const int*)d_in[5];
    float*       out         = (float*)d_out;

    hipMemsetAsync(out, 0, (size_t)out_size * sizeof(float), stream);

    dtw_spring_npath_kernel<<<dim3(NBLOCKS), dim3(BLOCK_SIZE), 0, stream>>>(
        kern, x, path_k, path_i, path_length, path_num, out);
}